// Round 2
// baseline (447.715 us; speedup 1.0000x reference)
//
#include <hip/hip_runtime.h>
#include <cstdint>
#include <cstddef>

#define N_NODES 100000
#define D 128
#define R 4
#define NE 150000
#define LAYERS 2
#define NROWS (R * N_NODES)   // 400000
#define CAP 16                // max in-degree per (rel,dst); Poisson(1.5) -> P(>16) ~ 1e-12
#define OVFS 12               // overflow slots per row (CAP - 4 inline)
#define TILES (N_NODES / 16)  // 6250
#define GRID 256              // persistent: one block per CU
#define TPB 512               // 8 waves: 4 producers + 4 consumers

typedef __attribute__((ext_vector_type(8))) short bf16x8;
typedef __attribute__((ext_vector_type(4))) float f32x4;
typedef __attribute__((ext_vector_type(4))) int i32x4;
typedef __attribute__((ext_vector_type(4))) unsigned short u16x4;

__device__ __forceinline__ unsigned short f2bf(float x) {
  union { float f; unsigned int u; } v; v.f = x;
  unsigned int u = v.u;
  return (unsigned short)((u + 0x7fffu + ((u >> 16) & 1u)) >> 16);  // RNE
}
__device__ __forceinline__ float bf2f(unsigned short u) {
  union { unsigned int i; float f; } v; v.i = ((unsigned int)u) << 16;
  return v.f;
}

// ---- count out-degree (int atomics); deg_i pre-zeroed ----
__global__ void count_kernel(const int* __restrict__ edges, int* __restrict__ deg_i) {
  int e = blockIdx.x * blockDim.x + threadIdx.x;
  int r = blockIdx.y;
  if (e >= NE) return;
  int src = edges[(size_t)(r * 2) * NE + e];
  atomicAdd(&deg_i[r * N_NODES + src], 1);
}

// fill padded edge records {src, rsqrt(deg_out[src])}; cursor counts in-degree.
// SoA layout: first 4 slots per dst packed per (rel,tile): rec2[r][tile][m][slot<4]
// (512 B contiguous per (rel,tile) -> 8 fully-used cache lines on read).
// Slots 4..15 go to ovf[rowg][slot-4]. Neither is zeroed: producer masks by cnt.
__global__ void fill_kernel(const int* __restrict__ edges, const int* __restrict__ deg_i,
                            int* __restrict__ cursor, int2* __restrict__ rec2,
                            int2* __restrict__ ovf) {
  int e = blockIdx.x * blockDim.x + threadIdx.x;
  int r = blockIdx.y;
  if (e >= NE) return;
  int src = edges[(size_t)(r * 2) * NE + e];
  int dst = edges[(size_t)(r * 2 + 1) * NE + e];
  float sc = rsqrtf(fmaxf((float)deg_i[r * N_NODES + src], 1.0f));
  int rowg = r * N_NODES + dst;
  int slot = atomicAdd(&cursor[rowg], 1);
  if (slot < 4) {
    int tile = dst >> 4, mm = dst & 15;
    rec2[(((size_t)(r * TILES + tile) * 16 + mm) << 2) + slot] = make_int2(src, __float_as_int(sc));
  } else if (slot < CAP) {
    ovf[(size_t)rowg * OVFS + (slot - 4)] = make_int2(src, __float_as_int(sc));
  }
}

// emb fp32 -> bf16; Wt transpose; bmean; s_in from cursor (runs AFTER fill)
__global__ void prep_kernel(const float* __restrict__ emb, const float* __restrict__ W,
                            const float* __restrict__ biases, const int* __restrict__ cursor,
                            unsigned short* __restrict__ hb, unsigned short* __restrict__ Wt,
                            float* __restrict__ bmean, float* __restrict__ s_in) {
  int t = blockIdx.x * blockDim.x + threadIdx.x;
  if (t < N_NODES * D / 4) {
    f32x4 v = *(const f32x4*)(emb + (size_t)t * 4);
    u16x4 o;
#pragma unroll
    for (int j = 0; j < 4; ++j) o[j] = f2bf(v[j]);
    *(u16x4*)(hb + (size_t)t * 4) = o;
  }
  if (t < LAYERS * R * D * D) {
    int k = t & 127;
    int c = (t >> 7) & 127;
    int lr = t >> 14;
    Wt[((size_t)lr << 14) | (c << 7) | k] = f2bf(W[((size_t)lr << 14) | (k << 7) | c]);
  }
  if (t < NROWS) s_in[t] = rsqrtf(fmaxf((float)cursor[t], 1.0f));
  if (t < LAYERS * D) {
    int l = t >> 7, cc = t & 127;
    float s = 0.f;
    for (int r = 0; r < R; ++r) s += biases[((size_t)l * R + r) * D + cc];
    bmean[t] = s * 0.25f;
  }
}

// ---- producer stage helpers (arrays by reference -> static indexing) ----
__device__ __forceinline__ void p_loadrec(const int* __restrict__ cnt,
                                          const int2* __restrict__ rec2,
                                          int r, int t, int m,
                                          int& cN, i32x4& r0, i32x4& r1) {
  const int2* rp = rec2 + (((size_t)(r * TILES + t) * 16 + m) << 2);
  cN = cnt[r * N_NODES + t * 16 + m];
  r0 = *(const i32x4*)(rp);
  r1 = *(const i32x4*)(rp + 2);
}

__device__ __forceinline__ int p_issue(const unsigned short* __restrict__ hb,
                                       const int2* __restrict__ ovf,
                                       int r, int t, int m, int q,
                                       int cN, i32x4 r0, i32x4 r1,
                                       float (&scs)[4], bf16x8 (&ld)[16], i32x4& tr) {
  int n = cN > CAP ? CAP : cN;
  int srcs[4] = { r0.x, r0.z, r1.x, r1.z };
  float sc[4] = { __int_as_float(r0.y), __int_as_float(r0.w),
                  __int_as_float(r1.y), __int_as_float(r1.w) };
#pragma unroll
  for (int e = 0; e < 4; ++e) {
    if (e >= n) { srcs[e] = 0; sc[e] = 0.f; }   // pads are garbage: mask (row 0 stays L1-hot)
    scs[e] = sc[e];
  }
  // hoist ALL 16 gather loads -> maximal lines in flight per wave
#pragma unroll
  for (int e = 0; e < 4; ++e) {
    const unsigned short* hp = hb + (size_t)srcs[e] * D + q * 8;
#pragma unroll
    for (int ks = 0; ks < 4; ++ks) ld[e * 4 + ks] = *(const bf16x8*)(hp + ks * 32);
  }
  if (__builtin_expect(n > 4, 0))   // prefetch overflow records 4,5 (covers 95% of tails)
    tr = *(const i32x4*)(ovf + (size_t)(r * N_NODES + t * 16 + m) * OVFS);
  return n;
}

__device__ __forceinline__ void p_accum(const unsigned short* __restrict__ hb,
                                        const int2* __restrict__ ovf,
                                        unsigned short* __restrict__ dstp,
                                        int r, int t, int m, int q,
                                        int n, const float (&scs)[4], const bf16x8 (&ld)[16],
                                        i32x4 tr) {
  float accf[4][8];
#pragma unroll
  for (int ks = 0; ks < 4; ++ks)
#pragma unroll
    for (int j = 0; j < 8; ++j) accf[ks][j] = 0.f;
  // rare tail first: issue its gathers, then main VALU hides their latency
  if (__builtin_expect(n > 4, 0)) {
    bool ok = n > 5;
    int sA = tr.x;
    int sB = ok ? tr.z : 0;
    float c0 = __int_as_float(tr.y);
    float c1 = ok ? __int_as_float(tr.w) : 0.f;
    const unsigned short* h0 = hb + (size_t)sA * D + q * 8;
    const unsigned short* h1 = hb + (size_t)sB * D + q * 8;
#pragma unroll
    for (int ks = 0; ks < 4; ++ks) {
      bf16x8 a0 = *(const bf16x8*)(h0 + ks * 32);
      bf16x8 a1 = *(const bf16x8*)(h1 + ks * 32);
#pragma unroll
      for (int j = 0; j < 8; ++j)
        accf[ks][j] += c0 * bf2f((unsigned short)a0[j]) + c1 * bf2f((unsigned short)a1[j]);
    }
    const int2* op = ovf + (size_t)(r * N_NODES + t * 16 + m) * OVFS;
    for (int i = 6; i < n; i += 2) {   // ultra-rare (P ~ 1%/wave)
      i32x4 rr = *(const i32x4*)(op + (i - 4));
      bool ok2 = (i + 1) < n;
      int s0 = rr.x;
      int s1 = ok2 ? rr.z : 0;
      float d0 = __int_as_float(rr.y);
      float d1 = ok2 ? __int_as_float(rr.w) : 0.f;
      const unsigned short* g0 = hb + (size_t)s0 * D + q * 8;
      const unsigned short* g1 = hb + (size_t)s1 * D + q * 8;
#pragma unroll
      for (int ks = 0; ks < 4; ++ks) {
        bf16x8 a0 = *(const bf16x8*)(g0 + ks * 32);
        bf16x8 a1 = *(const bf16x8*)(g1 + ks * 32);
#pragma unroll
        for (int j = 0; j < 8; ++j)
          accf[ks][j] += d0 * bf2f((unsigned short)a0[j]) + d1 * bf2f((unsigned short)a1[j]);
      }
    }
  }
#pragma unroll
  for (int e = 0; e < 4; ++e)
#pragma unroll
    for (int ks = 0; ks < 4; ++ks)
#pragma unroll
      for (int j = 0; j < 8; ++j)
        accf[ks][j] += scs[e] * bf2f((unsigned short)ld[e * 4 + ks][j]);
#pragma unroll
  for (int ks = 0; ks < 4; ++ks) {
    union { bf16x8 v; unsigned short s[8]; } u;
#pragma unroll
    for (int j = 0; j < 8; ++j) u.s[j] = f2bf(accf[ks][j]);
    *(bf16x8*)(dstp + (ks << 6) * 8) = u.v;
  }
}

// ======== persistent producer/consumer fused kernel =========================
// 256 blocks x 8 waves. Waves 0-3: gather-aggregate relation w, software-
// pipelined 2 tiles deep (tile it+1's gathers issued BEFORE tile it's VALU;
// rec prefetched 2 tiles ahead). Raw s_barrier + lgkmcnt(0) instead of
// __syncthreads so in-flight global prefetches survive the barrier
// (__syncthreads would drain vmcnt(0)). Waves 4-7: MFMA+epilogue of tile
// it-1, B-fragments in registers. One barrier per tile.
__global__ __launch_bounds__(TPB, 2) void fused_kernel(
    const unsigned short* __restrict__ hb,     // [N][128] bf16
    const int2* __restrict__ rec2,             // [R][TILES][16][4] {src, s_out}
    const int2* __restrict__ ovf,              // [NROWS][OVFS] overflow records
    const int* __restrict__ cnt,               // [NROWS] in-degree (may exceed CAP)
    const float* __restrict__ s_in,            // [NROWS]
    const unsigned short* __restrict__ Wt,     // layer: [R][128 col][128 k] bf16
    const float* __restrict__ bmean,           // [128]
    const unsigned short* __restrict__ resid_bf,
    float* __restrict__ out_f,
    unsigned short* __restrict__ out_bf) {
  __shared__ unsigned short t_lds[2][R * 4 * 64 * 8];  // 2 x 16 KB
  const int w = threadIdx.x >> 6;
  const int lane = threadIdx.x & 63;
  const int m = lane & 15;
  const int q = lane >> 4;
  const int bid = blockIdx.x;
  const int nt = (TILES - bid + GRID - 1) / GRID;   // >= 24 tiles for every block

  if (w < 4) {
    // -------------------- producer: relation w --------------------
    const int r = w;
    int cA, cB;
    i32x4 rA0, rA1, rB0, rB1, trA, trB;
    float scsA[4], scsB[4];
    bf16x8 ldA[16], ldB[16];
    int nA = 0, nB = 0;

    // prologue: tile0 rec -> issue tile0 gathers; tile1 rec in flight
    p_loadrec(cnt, rec2, r, bid, m, cA, rA0, rA1);
    nA = p_issue(hb, ovf, r, bid, m, q, cA, rA0, rA1, scsA, ldA, trA);
    p_loadrec(cnt, rec2, r, bid + GRID, m, cB, rB0, rB1);

    for (int it = 0; it < nt; ++it) {
      const int tcur = bid + it * GRID;
      unsigned short* dstp = &t_lds[it & 1][(((r * 4) << 6) + lane) * 8];
      if ((it & 1) == 0) {
        if (it + 1 < nt) {
          nB = p_issue(hb, ovf, r, tcur + GRID, m, q, cB, rB0, rB1, scsB, ldB, trB);
          int t2 = tcur + 2 * GRID; if (t2 >= TILES) t2 = bid;  // clamped load, discarded
          p_loadrec(cnt, rec2, r, t2, m, cA, rA0, rA1);
        }
        p_accum(hb, ovf, dstp, r, tcur, m, q, nA, scsA, ldA, trA);
      } else {
        if (it + 1 < nt) {
          nA = p_issue(hb, ovf, r, tcur + GRID, m, q, cA, rA0, rA1, scsA, ldA, trA);
          int t2 = tcur + 2 * GRID; if (t2 >= TILES) t2 = bid;
          p_loadrec(cnt, rec2, r, t2, m, cB, rB0, rB1);
        }
        p_accum(hb, ovf, dstp, r, tcur, m, q, nB, scsB, ldB, trB);
      }
      asm volatile("s_waitcnt lgkmcnt(0)" ::: "memory");  // LDS writes visible; vmcnt NOT drained
      __builtin_amdgcn_s_barrier();
    }
    asm volatile("s_waitcnt lgkmcnt(0)" ::: "memory");
    __builtin_amdgcn_s_barrier();                         // match consumer's nt+1 barriers
  } else {
    // -------------------- consumer: cols [cw*32, cw*32+32) --------------------
    const int cw = w - 4;
    bf16x8 breg[R][4][2];
#pragma unroll
    for (int r = 0; r < R; ++r) {
      const unsigned short* wr = Wt + ((size_t)r << 14);
#pragma unroll
      for (int ks = 0; ks < 4; ++ks)
#pragma unroll
        for (int c = 0; c < 2; ++c) {
          int ct = cw * 2 + c;
          breg[r][ks][c] = *(const bf16x8*)(wr + ((ct * 16 + m) << 7) + ks * 32 + q * 8);
        }
    }
    for (int it = 0; it < nt + 1; ++it) {
      if (it > 0) {
        const int tile = bid + (it - 1) * GRID;
        const int pb = (it - 1) & 1;
        float oacc[2][4];
#pragma unroll
        for (int c = 0; c < 2; ++c)
#pragma unroll
          for (int i = 0; i < 4; ++i) oacc[c][i] = 0.f;
#pragma unroll
        for (int r = 0; r < R; ++r) {
          f32x4 acc2[2];
#pragma unroll
          for (int c = 0; c < 2; ++c) acc2[c] = (f32x4){0.f, 0.f, 0.f, 0.f};
#pragma unroll
          for (int ks = 0; ks < 4; ++ks) {
            bf16x8 a = *(const bf16x8*)&t_lds[pb][(((r * 4 + ks) << 6) + lane) * 8];
#pragma unroll
            for (int c = 0; c < 2; ++c)
              acc2[c] = __builtin_amdgcn_mfma_f32_16x16x32_bf16(a, breg[r][ks][c], acc2[c], 0, 0, 0);
          }
          f32x4 s = *(const f32x4*)(s_in + (size_t)r * N_NODES + tile * 16 + q * 4);
#pragma unroll
          for (int c = 0; c < 2; ++c)
#pragma unroll
            for (int i = 0; i < 4; ++i) oacc[c][i] += s[i] * acc2[c][i];
        }
#pragma unroll
        for (int c = 0; c < 2; ++c) {
          int colx = (cw * 2 + c) * 16 + m;
          float bm = bmean[colx];
#pragma unroll
          for (int i = 0; i < 4; ++i) {
            int row = tile * 16 + q * 4 + i;
            float v = oacc[c][i] * 0.25f + bm;
            v = (v >= 0.f) ? v : 0.2f * v;
            if (resid_bf) v += bf2f(resid_bf[(size_t)row * D + colx]);
            if (out_f) out_f[(size_t)row * D + colx] = v;
            else       out_bf[(size_t)row * D + colx] = f2bf(v);
          }
        }
      }
      asm volatile("s_waitcnt lgkmcnt(0)" ::: "memory");
      __builtin_amdgcn_s_barrier();
    }
  }
}

extern "C" void kernel_launch(void* const* d_in, const int* in_sizes, int n_in,
                              void* d_out, int out_size, void* d_ws, size_t ws_size,
                              hipStream_t stream) {
  const float* emb    = (const float*)d_in[0];
  const float* W      = (const float*)d_in[1];
  const float* biases = (const float*)d_in[2];
  const int*   edges  = (const int*)d_in[3];
  float* out = (float*)d_out;
  char* ws = (char*)d_ws;

  size_t off = 0;
  auto alloc = [&](size_t bytes) { size_t o = off; off += (bytes + 255) & ~255ull; return o; };
  // only the int arrays (deg_i | cursor) need zeroing -> 3.2 MB memset
  int* ints      = (int*)(ws + alloc((size_t)2 * NROWS * 4));   // [deg_i | cursor]
  int* deg_i     = ints;
  int* cursor    = ints + NROWS;
  size_t zero_bytes = off;
  int2* rec2     = (int2*)(ws + alloc((size_t)R * TILES * 16 * 4 * 8));  // 12.8 MB, NOT zeroed
  int2* ovf      = (int2*)(ws + alloc((size_t)NROWS * OVFS * 8));        // 38.4 MB, NOT zeroed
  float* s_in    = (float*)(ws + alloc((size_t)NROWS * 4));
  unsigned short* hb  = (unsigned short*)(ws + alloc((size_t)N_NODES * D * 2));
  unsigned short* hb2 = (unsigned short*)(ws + alloc((size_t)N_NODES * D * 2));
  unsigned short* Wt  = (unsigned short*)(ws + alloc((size_t)LAYERS * R * D * D * 2));
  float* bmean   = (float*)(ws + alloc((size_t)LAYERS * D * 4));
  (void)ws_size;

  // ---- prep: memset -> count -> fill -> prep (4 dispatches) ----
  hipMemsetAsync(ws, 0, zero_bytes, stream);
  count_kernel<<<dim3((NE + 255) / 256, R), 256, 0, stream>>>(edges, deg_i);
  fill_kernel<<<dim3((NE + 255) / 256, R), 256, 0, stream>>>(edges, deg_i, cursor, rec2, ovf);
  prep_kernel<<<(N_NODES * D / 4 + 255) / 256, 256, 0, stream>>>(
      emb, W, biases, cursor, hb, Wt, bmean, s_in);

  // layer 0: emb(bf16) -> hb2(bf16), no residual
  fused_kernel<<<GRID, TPB, 0, stream>>>(
      hb, rec2, ovf, cursor, s_in, Wt, bmean, nullptr, nullptr, hb2);
  // layer 1: hb2 -> out(fp32), residual = hb2
  fused_kernel<<<GRID, TPB, 0, stream>>>(
      hb2, rec2, ovf, cursor, s_in, Wt + (size_t)R * D * D, bmean + D, hb2, out, nullptr);
}

// Round 3
// 443.758 us; speedup vs baseline: 1.0089x; 1.0089x over previous
//
#include <hip/hip_runtime.h>
#include <cstdint>
#include <cstddef>

#define N_NODES 100000
#define D 128
#define R 4
#define NE 150000
#define LAYERS 2
#define NROWS (R * N_NODES)   // 400000
#define CAP 16                // max in-degree per (rel,dst); Poisson(1.5) -> P(>16) ~ 1e-12
#define OVFS 12               // overflow slots per row (CAP - 4 inline)
#define TILES (N_NODES / 16)  // 6250
#define GRID 256              // persistent: one block per CU
#define TPB 512               // 8 waves: 4 producers + 4 consumers

typedef __attribute__((ext_vector_type(8))) short bf16x8;
typedef __attribute__((ext_vector_type(4))) float f32x4;
typedef __attribute__((ext_vector_type(4))) int i32x4;
typedef __attribute__((ext_vector_type(4))) unsigned short u16x4;

__device__ __forceinline__ unsigned short f2bf(float x) {
  union { float f; unsigned int u; } v; v.f = x;
  unsigned int u = v.u;
  return (unsigned short)((u + 0x7fffu + ((u >> 16) & 1u)) >> 16);  // RNE
}
__device__ __forceinline__ float bf2f(unsigned short u) {
  union { unsigned int i; float f; } v; v.i = ((unsigned int)u) << 16;
  return v.f;
}

// ---- prep1: out-degree count + emb fp32->bf16 + Wt transpose + bmean ------
// (count needs only edges; conversions need only emb/W/biases -> one dispatch)
__global__ void prep1_kernel(const float* __restrict__ emb, const float* __restrict__ W,
                             const float* __restrict__ biases, const int* __restrict__ edges,
                             int* __restrict__ deg_i, unsigned short* __restrict__ hb,
                             unsigned short* __restrict__ Wt, float* __restrict__ bmean) {
  int t = blockIdx.x * blockDim.x + threadIdx.x;
  if (t < N_NODES * D / 4) {
    f32x4 v = *(const f32x4*)(emb + (size_t)t * 4);
    u16x4 o;
#pragma unroll
    for (int j = 0; j < 4; ++j) o[j] = f2bf(v[j]);
    *(u16x4*)(hb + (size_t)t * 4) = o;
  }
  if (t < NE * R) {
    int r = t / NE;
    int e = t - r * NE;
    int src = edges[(size_t)(r * 2) * NE + e];
    atomicAdd(&deg_i[r * N_NODES + src], 1);
  }
  if (t < LAYERS * R * D * D) {
    int k = t & 127;
    int c = (t >> 7) & 127;
    int lr = t >> 14;
    Wt[((size_t)lr << 14) | (c << 7) | k] = f2bf(W[((size_t)lr << 14) | (k << 7) | c]);
  }
  if (t < LAYERS * D) {
    int l = t >> 7, cc = t & 127;
    float s = 0.f;
    for (int r = 0; r < R; ++r) s += biases[((size_t)l * R + r) * D + cc];
    bmean[t] = s * 0.25f;
  }
}

// fill padded edge records {src, rsqrt(deg_out[src])}; cursor counts in-degree.
// SoA layout: first 4 slots per dst packed per (rel,tile): rec2[r][tile][m][slot<4]
// (512 B contiguous per (rel,tile) -> 8 fully-used cache lines on read).
// Slots 4..15 go to ovf[rowg][slot-4]. Neither is zeroed: producer masks by cnt.
__global__ void fill_kernel(const int* __restrict__ edges, const int* __restrict__ deg_i,
                            int* __restrict__ cursor, int2* __restrict__ rec2,
                            int2* __restrict__ ovf) {
  int e = blockIdx.x * blockDim.x + threadIdx.x;
  int r = blockIdx.y;
  if (e >= NE) return;
  int src = edges[(size_t)(r * 2) * NE + e];
  int dst = edges[(size_t)(r * 2 + 1) * NE + e];
  float sc = rsqrtf(fmaxf((float)deg_i[r * N_NODES + src], 1.0f));
  int rowg = r * N_NODES + dst;
  int slot = atomicAdd(&cursor[rowg], 1);
  if (slot < 4) {
    int tile = dst >> 4, mm = dst & 15;
    rec2[(((size_t)(r * TILES + tile) * 16 + mm) << 2) + slot] = make_int2(src, __float_as_int(sc));
  } else if (slot < CAP) {
    ovf[(size_t)rowg * OVFS + (slot - 4)] = make_int2(src, __float_as_int(sc));
  }
}

// ---- producer stage helpers (arrays by reference -> static indexing) ----
__device__ __forceinline__ void p_loadrec(const int* __restrict__ cnt,
                                          const int2* __restrict__ rec2,
                                          int r, int t, int m,
                                          int& cN, i32x4& r0, i32x4& r1) {
  const int2* rp = rec2 + (((size_t)(r * TILES + t) * 16 + m) << 2);
  cN = cnt[r * N_NODES + t * 16 + m];
  r0 = *(const i32x4*)(rp);
  r1 = *(const i32x4*)(rp + 2);
}

__device__ __forceinline__ int p_issue(const unsigned short* __restrict__ hb,
                                       const int2* __restrict__ ovf,
                                       int r, int t, int m, int q,
                                       int cN, i32x4 r0, i32x4 r1,
                                       float (&scs)[4], bf16x8 (&ld)[16], i32x4& tr) {
  int n = cN > CAP ? CAP : cN;
  int srcs[4] = { r0.x, r0.z, r1.x, r1.z };
  float sc[4] = { __int_as_float(r0.y), __int_as_float(r0.w),
                  __int_as_float(r1.y), __int_as_float(r1.w) };
#pragma unroll
  for (int e = 0; e < 4; ++e) {
    if (e >= n) { srcs[e] = 0; sc[e] = 0.f; }   // pads are garbage: mask (row 0 lanes coalesce + stay L1-hot)
    scs[e] = sc[e];
  }
  // hoist ALL 16 gather loads -> one vmcnt wait per tile instead of 4 serial ones
#pragma unroll
  for (int e = 0; e < 4; ++e) {
    const unsigned short* hp = hb + (size_t)srcs[e] * D + q * 8;
#pragma unroll
    for (int ks = 0; ks < 4; ++ks) ld[e * 4 + ks] = *(const bf16x8*)(hp + ks * 32);
  }
  if (__builtin_expect(n > 4, 0))   // prefetch overflow records 4,5 (covers 95% of tails)
    tr = *(const i32x4*)(ovf + (size_t)(r * N_NODES + t * 16 + m) * OVFS);
  return n;
}

__device__ __forceinline__ void p_accum(const unsigned short* __restrict__ hb,
                                        const int2* __restrict__ ovf,
                                        unsigned short* __restrict__ dstp,
                                        int r, int t, int m, int q,
                                        int n, const float (&scs)[4], const bf16x8 (&ld)[16],
                                        i32x4 tr) {
  float accf[4][8];
#pragma unroll
  for (int ks = 0; ks < 4; ++ks)
#pragma unroll
    for (int j = 0; j < 8; ++j) accf[ks][j] = 0.f;
  // rare tail first: issue its gathers, then main VALU hides their latency
  if (__builtin_expect(n > 4, 0)) {
    bool ok = n > 5;
    int sA = tr.x;
    int sB = ok ? tr.z : 0;
    float c0 = __int_as_float(tr.y);
    float c1 = ok ? __int_as_float(tr.w) : 0.f;
    const unsigned short* h0 = hb + (size_t)sA * D + q * 8;
    const unsigned short* h1 = hb + (size_t)sB * D + q * 8;
#pragma unroll
    for (int ks = 0; ks < 4; ++ks) {
      bf16x8 a0 = *(const bf16x8*)(h0 + ks * 32);
      bf16x8 a1 = *(const bf16x8*)(h1 + ks * 32);
#pragma unroll
      for (int j = 0; j < 8; ++j)
        accf[ks][j] += c0 * bf2f((unsigned short)a0[j]) + c1 * bf2f((unsigned short)a1[j]);
    }
    const int2* op = ovf + (size_t)(r * N_NODES + t * 16 + m) * OVFS;
    for (int i = 6; i < n; i += 2) {   // ultra-rare (P ~ 1%/wave)
      i32x4 rr = *(const i32x4*)(op + (i - 4));
      bool ok2 = (i + 1) < n;
      int s0 = rr.x;
      int s1 = ok2 ? rr.z : 0;
      float d0 = __int_as_float(rr.y);
      float d1 = ok2 ? __int_as_float(rr.w) : 0.f;
      const unsigned short* g0 = hb + (size_t)s0 * D + q * 8;
      const unsigned short* g1 = hb + (size_t)s1 * D + q * 8;
#pragma unroll
      for (int ks = 0; ks < 4; ++ks) {
        bf16x8 a0 = *(const bf16x8*)(g0 + ks * 32);
        bf16x8 a1 = *(const bf16x8*)(g1 + ks * 32);
#pragma unroll
        for (int j = 0; j < 8; ++j)
          accf[ks][j] += d0 * bf2f((unsigned short)a0[j]) + d1 * bf2f((unsigned short)a1[j]);
      }
    }
  }
#pragma unroll
  for (int e = 0; e < 4; ++e)
#pragma unroll
    for (int ks = 0; ks < 4; ++ks)
#pragma unroll
      for (int j = 0; j < 8; ++j)
        accf[ks][j] += scs[e] * bf2f((unsigned short)ld[e * 4 + ks][j]);
#pragma unroll
  for (int ks = 0; ks < 4; ++ks) {
    union { bf16x8 v; unsigned short s[8]; } u;
#pragma unroll
    for (int j = 0; j < 8; ++j) u.s[j] = f2bf(accf[ks][j]);
    *(bf16x8*)(dstp + (ks << 6) * 8) = u.v;
  }
}

// ======== persistent producer/consumer fused kernel =========================
// 256 blocks x 8 waves. Waves 0-3: gather-aggregate relation w, software-
// pipelined 2 tiles deep (tile it+1's gathers issued BEFORE tile it's VALU;
// rec prefetched 2 tiles ahead). Raw s_barrier + lgkmcnt(0) instead of
// __syncthreads so in-flight global prefetches survive the barrier
// (__syncthreads would drain vmcnt(0)). Waves 4-7: MFMA+epilogue of tile
// it-1, B-fragments in registers. One barrier per tile.
// __launch_bounds__(512, 1): VGPR cap 256 -- the 2-deep pipeline holds
// ldA[16]+ldB[16] (128 VGPRs) live; the previous (512,2) capped at 128 and
// spilled everything to scratch (WRITE_SIZE 50->196 MB, +50us). 1 block/CU
// is fine: round 1 showed a 2nd co-resident block buys nothing.
__global__ __launch_bounds__(TPB, 1) void fused_kernel(
    const unsigned short* __restrict__ hb,     // [N][128] bf16
    const int2* __restrict__ rec2,             // [R][TILES][16][4] {src, s_out}
    const int2* __restrict__ ovf,              // [NROWS][OVFS] overflow records
    const int* __restrict__ cnt,               // [NROWS] in-degree (may exceed CAP)
    const unsigned short* __restrict__ Wt,     // layer: [R][128 col][128 k] bf16
    const float* __restrict__ bmean,           // [128]
    const unsigned short* __restrict__ resid_bf,
    float* __restrict__ out_f,
    unsigned short* __restrict__ out_bf) {
  __shared__ unsigned short t_lds[2][R * 4 * 64 * 8];  // 2 x 16 KB
  const int w = threadIdx.x >> 6;
  const int lane = threadIdx.x & 63;
  const int m = lane & 15;
  const int q = lane >> 4;
  const int bid = blockIdx.x;
  const int nt = (TILES - bid + GRID - 1) / GRID;   // >= 24 tiles for every block

  if (w < 4) {
    // -------------------- producer: relation w --------------------
    const int r = w;
    int cA, cB;
    i32x4 rA0, rA1, rB0, rB1, trA, trB;
    float scsA[4], scsB[4];
    bf16x8 ldA[16], ldB[16];
    int nA = 0, nB = 0;

    // prologue: tile0 rec -> issue tile0 gathers; tile1 rec in flight
    p_loadrec(cnt, rec2, r, bid, m, cA, rA0, rA1);
    nA = p_issue(hb, ovf, r, bid, m, q, cA, rA0, rA1, scsA, ldA, trA);
    p_loadrec(cnt, rec2, r, bid + GRID, m, cB, rB0, rB1);

    for (int it = 0; it < nt; ++it) {
      const int tcur = bid + it * GRID;
      unsigned short* dstp = &t_lds[it & 1][(((r * 4) << 6) + lane) * 8];
      if ((it & 1) == 0) {
        if (it + 1 < nt) {
          nB = p_issue(hb, ovf, r, tcur + GRID, m, q, cB, rB0, rB1, scsB, ldB, trB);
          int t2 = tcur + 2 * GRID; if (t2 >= TILES) t2 = bid;  // clamped load, discarded
          p_loadrec(cnt, rec2, r, t2, m, cA, rA0, rA1);
        }
        p_accum(hb, ovf, dstp, r, tcur, m, q, nA, scsA, ldA, trA);
      } else {
        if (it + 1 < nt) {
          nA = p_issue(hb, ovf, r, tcur + GRID, m, q, cA, rA0, rA1, scsA, ldA, trA);
          int t2 = tcur + 2 * GRID; if (t2 >= TILES) t2 = bid;
          p_loadrec(cnt, rec2, r, t2, m, cB, rB0, rB1);
        }
        p_accum(hb, ovf, dstp, r, tcur, m, q, nB, scsB, ldB, trB);
      }
      asm volatile("s_waitcnt lgkmcnt(0)" ::: "memory");  // LDS writes visible; vmcnt NOT drained
      __builtin_amdgcn_s_barrier();
    }
    asm volatile("s_waitcnt lgkmcnt(0)" ::: "memory");
    __builtin_amdgcn_s_barrier();                         // match consumer's nt+1 barriers
  } else {
    // -------------------- consumer: cols [cw*32, cw*32+32) --------------------
    const int cw = w - 4;
    bf16x8 breg[R][4][2];
#pragma unroll
    for (int r = 0; r < R; ++r) {
      const unsigned short* wr = Wt + ((size_t)r << 14);
#pragma unroll
      for (int ks = 0; ks < 4; ++ks)
#pragma unroll
        for (int c = 0; c < 2; ++c) {
          int ct = cw * 2 + c;
          breg[r][ks][c] = *(const bf16x8*)(wr + ((ct * 16 + m) << 7) + ks * 32 + q * 8);
        }
    }
    for (int it = 0; it < nt + 1; ++it) {
      if (it > 0) {
        const int tile = bid + (it - 1) * GRID;
        const int pb = (it - 1) & 1;
        float oacc[2][4];
#pragma unroll
        for (int c = 0; c < 2; ++c)
#pragma unroll
          for (int i = 0; i < 4; ++i) oacc[c][i] = 0.f;
#pragma unroll
        for (int r = 0; r < R; ++r) {
          f32x4 acc2[2];
#pragma unroll
          for (int c = 0; c < 2; ++c) acc2[c] = (f32x4){0.f, 0.f, 0.f, 0.f};
#pragma unroll
          for (int ks = 0; ks < 4; ++ks) {
            bf16x8 a = *(const bf16x8*)&t_lds[pb][(((r * 4 + ks) << 6) + lane) * 8];
#pragma unroll
            for (int c = 0; c < 2; ++c)
              acc2[c] = __builtin_amdgcn_mfma_f32_16x16x32_bf16(a, breg[r][ks][c], acc2[c], 0, 0, 0);
          }
          // s_in computed inline from in-degree (replaces the s_in array+pass)
          i32x4 ci = *(const i32x4*)(cnt + (size_t)r * N_NODES + tile * 16 + q * 4);
#pragma unroll
          for (int c = 0; c < 2; ++c)
#pragma unroll
            for (int i = 0; i < 4; ++i)
              oacc[c][i] += rsqrtf(fmaxf((float)ci[i], 1.0f)) * acc2[c][i];
        }
#pragma unroll
        for (int c = 0; c < 2; ++c) {
          int colx = (cw * 2 + c) * 16 + m;
          float bm = bmean[colx];
#pragma unroll
          for (int i = 0; i < 4; ++i) {
            int row = tile * 16 + q * 4 + i;
            float v = oacc[c][i] * 0.25f + bm;
            v = (v >= 0.f) ? v : 0.2f * v;
            if (resid_bf) v += bf2f(resid_bf[(size_t)row * D + colx]);
            if (out_f) out_f[(size_t)row * D + colx] = v;
            else       out_bf[(size_t)row * D + colx] = f2bf(v);
          }
        }
      }
      asm volatile("s_waitcnt lgkmcnt(0)" ::: "memory");
      __builtin_amdgcn_s_barrier();
    }
  }
}

extern "C" void kernel_launch(void* const* d_in, const int* in_sizes, int n_in,
                              void* d_out, int out_size, void* d_ws, size_t ws_size,
                              hipStream_t stream) {
  const float* emb    = (const float*)d_in[0];
  const float* W      = (const float*)d_in[1];
  const float* biases = (const float*)d_in[2];
  const int*   edges  = (const int*)d_in[3];
  float* out = (float*)d_out;
  char* ws = (char*)d_ws;

  size_t off = 0;
  auto alloc = [&](size_t bytes) { size_t o = off; off += (bytes + 255) & ~255ull; return o; };
  // only the int arrays (deg_i | cursor) need zeroing -> 3.2 MB memset
  int* ints      = (int*)(ws + alloc((size_t)2 * NROWS * 4));   // [deg_i | cursor]
  int* deg_i     = ints;
  int* cursor    = ints + NROWS;
  size_t zero_bytes = off;
  int2* rec2     = (int2*)(ws + alloc((size_t)R * TILES * 16 * 4 * 8));  // 12.8 MB, NOT zeroed
  int2* ovf      = (int2*)(ws + alloc((size_t)NROWS * OVFS * 8));        // 38.4 MB, NOT zeroed
  unsigned short* hb  = (unsigned short*)(ws + alloc((size_t)N_NODES * D * 2));
  unsigned short* hb2 = (unsigned short*)(ws + alloc((size_t)N_NODES * D * 2));
  unsigned short* Wt  = (unsigned short*)(ws + alloc((size_t)LAYERS * R * D * D * 2));
  float* bmean   = (float*)(ws + alloc((size_t)LAYERS * D * 4));
  (void)ws_size;

  // ---- prep: memset -> prep1(count+conversions) -> fill (3 dispatches) ----
  hipMemsetAsync(ws, 0, zero_bytes, stream);
  prep1_kernel<<<(N_NODES * D / 4 + 255) / 256, 256, 0, stream>>>(
      emb, W, biases, edges, deg_i, hb, Wt, bmean);
  fill_kernel<<<dim3((NE + 255) / 256, R), 256, 0, stream>>>(edges, deg_i, cursor, rec2, ovf);

  // layer 0: emb(bf16) -> hb2(bf16), no residual
  fused_kernel<<<GRID, TPB, 0, stream>>>(
      hb, rec2, ovf, cursor, Wt, bmean, nullptr, nullptr, hb2);
  // layer 1: hb2 -> out(fp32), residual = hb2
  fused_kernel<<<GRID, TPB, 0, stream>>>(
      hb2, rec2, ovf, cursor, Wt + (size_t)R * D * D, bmean + D, hb2, out, nullptr);
}

// Round 4
// 363.803 us; speedup vs baseline: 1.2307x; 1.2198x over previous
//
#include <hip/hip_runtime.h>
#include <cstdint>
#include <cstddef>

#define N_NODES 100000
#define D 128
#define R 4
#define NE 150000
#define LAYERS 2
#define NROWS (R * N_NODES)   // 400000
#define CAP 16                // max in-degree per (rel,dst); Poisson(1.5) -> P(>16) ~ 1e-12
#define OVFS 12               // overflow slots per row (CAP - 4 inline)
#define TILES (N_NODES / 16)  // 6250
#define GRID 256              // persistent: one block per CU
#define TPB 512               // 8 waves: 4 producers + 4 consumers

typedef __attribute__((ext_vector_type(8))) short bf16x8;
typedef __attribute__((ext_vector_type(4))) float f32x4;
typedef __attribute__((ext_vector_type(4))) int i32x4;
typedef __attribute__((ext_vector_type(4))) unsigned short u16x4;

__device__ __forceinline__ unsigned short f2bf(float x) {
  union { float f; unsigned int u; } v; v.f = x;
  unsigned int u = v.u;
  return (unsigned short)((u + 0x7fffu + ((u >> 16) & 1u)) >> 16);  // RNE
}
__device__ __forceinline__ float bf2f(unsigned short u) {
  union { unsigned int i; float f; } v; v.i = ((unsigned int)u) << 16;
  return v.f;
}

// ---- prep1: out-degree count + emb fp32->bf16 + Wt transpose + bmean ------
__global__ void prep1_kernel(const float* __restrict__ emb, const float* __restrict__ W,
                             const float* __restrict__ biases, const int* __restrict__ edges,
                             int* __restrict__ deg_i, unsigned short* __restrict__ hb,
                             unsigned short* __restrict__ Wt, float* __restrict__ bmean) {
  int t = blockIdx.x * blockDim.x + threadIdx.x;
  if (t < N_NODES * D / 4) {
    f32x4 v = *(const f32x4*)(emb + (size_t)t * 4);
    u16x4 o;
#pragma unroll
    for (int j = 0; j < 4; ++j) o[j] = f2bf(v[j]);
    *(u16x4*)(hb + (size_t)t * 4) = o;
  }
  if (t < NE * R) {
    int r = t / NE;
    int e = t - r * NE;
    int src = edges[(size_t)(r * 2) * NE + e];
    atomicAdd(&deg_i[r * N_NODES + src], 1);
  }
  if (t < LAYERS * R * D * D) {
    int k = t & 127;
    int c = (t >> 7) & 127;
    int lr = t >> 14;
    Wt[((size_t)lr << 14) | (c << 7) | k] = f2bf(W[((size_t)lr << 14) | (k << 7) | c]);
  }
  if (t < LAYERS * D) {
    int l = t >> 7, cc = t & 127;
    float s = 0.f;
    for (int r = 0; r < R; ++r) s += biases[((size_t)l * R + r) * D + cc];
    bmean[t] = s * 0.25f;
  }
}

// fill padded edge records {src, rsqrt(deg_out[src])}; cursor counts in-degree.
// SoA: slots 0..3 packed per (rel,tile): rec2[r][tile][m][slot] (512 B/tile-rel).
// Slots 4..15 -> ovf[rowg][slot-4]. Neither zeroed: producer masks by cnt.
__global__ void fill_kernel(const int* __restrict__ edges, const int* __restrict__ deg_i,
                            int* __restrict__ cursor, int2* __restrict__ rec2,
                            int2* __restrict__ ovf) {
  int e = blockIdx.x * blockDim.x + threadIdx.x;
  int r = blockIdx.y;
  if (e >= NE) return;
  int src = edges[(size_t)(r * 2) * NE + e];
  int dst = edges[(size_t)(r * 2 + 1) * NE + e];
  float sc = rsqrtf(fmaxf((float)deg_i[r * N_NODES + src], 1.0f));
  int rowg = r * N_NODES + dst;
  int slot = atomicAdd(&cursor[rowg], 1);
  if (slot < 4) {
    int tile = dst >> 4, mm = dst & 15;
    rec2[(((size_t)(r * TILES + tile) * 16 + mm) << 2) + slot] = make_int2(src, __float_as_int(sc));
  } else if (slot < CAP) {
    ovf[(size_t)rowg * OVFS + (slot - 4)] = make_int2(src, __float_as_int(sc));
  }
}

// ===== producer pipeline stage: ALL NAMED VARIABLES (rule #20: any branch-
// selected array goes to scratch -- R2/R3 lost 50us + 146MB writes to that).
#define DECL_ST(P) \
  bf16x8 P##g0, P##g1, P##g2, P##g3, P##g4, P##g5, P##g6, P##g7, \
         P##g8, P##g9, P##g10, P##g11, P##g12, P##g13, P##g14, P##g15; \
  float P##c0 = 0.f, P##c1 = 0.f, P##c2 = 0.f, P##c3 = 0.f; \
  i32x4 P##tr = (i32x4){0, 0, 0, 0}; \
  int P##n = 0

// load rec quad + count for (r, tile TT, row m)
#define P_LOADREC(CN, R0V, R1V, TT) do { \
  const int2* rp_ = rec2 + (((size_t)(r * TILES + (TT)) * 16 + m) << 2); \
  CN = cnt[r * N_NODES + (TT) * 16 + m]; \
  R0V = *(const i32x4*)(rp_); \
  R1V = *(const i32x4*)(rp_ + 2); \
} while (0)

// issue all 16 gather loads (+rare ovf prefetch) for tile TT into stage P
#define P_ISSUE(P, CN, R0V, R1V, TT) do { \
  int n_ = (CN) > CAP ? CAP : (CN); \
  int a0_ = (R0V).x, a1_ = (R0V).z, a2_ = (R1V).x, a3_ = (R1V).z; \
  float b0_ = __int_as_float((R0V).y), b1_ = __int_as_float((R0V).w); \
  float b2_ = __int_as_float((R1V).y), b3_ = __int_as_float((R1V).w); \
  if (n_ < 1) { a0_ = 0; b0_ = 0.f; } \
  if (n_ < 2) { a1_ = 0; b1_ = 0.f; } \
  if (n_ < 3) { a2_ = 0; b2_ = 0.f; } \
  if (n_ < 4) { a3_ = 0; b3_ = 0.f; } \
  const unsigned short* h0_ = hb + (size_t)a0_ * D + q * 8; \
  const unsigned short* h1_ = hb + (size_t)a1_ * D + q * 8; \
  const unsigned short* h2_ = hb + (size_t)a2_ * D + q * 8; \
  const unsigned short* h3_ = hb + (size_t)a3_ * D + q * 8; \
  P##g0  = *(const bf16x8*)(h0_);      P##g1  = *(const bf16x8*)(h0_ + 32); \
  P##g2  = *(const bf16x8*)(h0_ + 64); P##g3  = *(const bf16x8*)(h0_ + 96); \
  P##g4  = *(const bf16x8*)(h1_);      P##g5  = *(const bf16x8*)(h1_ + 32); \
  P##g6  = *(const bf16x8*)(h1_ + 64); P##g7  = *(const bf16x8*)(h1_ + 96); \
  P##g8  = *(const bf16x8*)(h2_);      P##g9  = *(const bf16x8*)(h2_ + 32); \
  P##g10 = *(const bf16x8*)(h2_ + 64); P##g11 = *(const bf16x8*)(h2_ + 96); \
  P##g12 = *(const bf16x8*)(h3_);      P##g13 = *(const bf16x8*)(h3_ + 32); \
  P##g14 = *(const bf16x8*)(h3_ + 64); P##g15 = *(const bf16x8*)(h3_ + 96); \
  P##c0 = b0_; P##c1 = b1_; P##c2 = b2_; P##c3 = b3_; P##n = n_; \
  if (__builtin_expect(n_ > 4, 0)) \
    P##tr = *(const i32x4*)(ovf + (size_t)(r * N_NODES + (TT) * 16 + m) * OVFS); \
} while (0)

// accumulate stage P (tile TT) and write bf16 result to LDS at DSTP
#define P_ACCUM(P, TT, DSTP) do { \
  float accf[4][8]; \
  _Pragma("unroll") for (int k_ = 0; k_ < 4; ++k_) \
    _Pragma("unroll") for (int j_ = 0; j_ < 8; ++j_) accf[k_][j_] = 0.f; \
  if (__builtin_expect(P##n > 4, 0)) { \
    bool ok_ = P##n > 5; \
    int sA_ = P##tr.x, sB_ = ok_ ? P##tr.z : 0; \
    float cA_ = __int_as_float(P##tr.y), cB_ = ok_ ? __int_as_float(P##tr.w) : 0.f; \
    const unsigned short* hA_ = hb + (size_t)sA_ * D + q * 8; \
    const unsigned short* hB_ = hb + (size_t)sB_ * D + q * 8; \
    _Pragma("unroll") for (int k_ = 0; k_ < 4; ++k_) { \
      bf16x8 x0_ = *(const bf16x8*)(hA_ + k_ * 32); \
      bf16x8 x1_ = *(const bf16x8*)(hB_ + k_ * 32); \
      _Pragma("unroll") for (int j_ = 0; j_ < 8; ++j_) \
        accf[k_][j_] += cA_ * bf2f((unsigned short)x0_[j_]) + cB_ * bf2f((unsigned short)x1_[j_]); \
    } \
    const int2* op_ = ovf + (size_t)(r * N_NODES + (TT) * 16 + m) * OVFS; \
    for (int i_ = 6; i_ < P##n; i_ += 2) { \
      i32x4 rr_ = *(const i32x4*)(op_ + (i_ - 4)); \
      bool o2_ = (i_ + 1) < P##n; \
      int s0_ = rr_.x, s1_ = o2_ ? rr_.z : 0; \
      float d0_ = __int_as_float(rr_.y), d1_ = o2_ ? __int_as_float(rr_.w) : 0.f; \
      const unsigned short* y0_ = hb + (size_t)s0_ * D + q * 8; \
      const unsigned short* y1_ = hb + (size_t)s1_ * D + q * 8; \
      _Pragma("unroll") for (int k_ = 0; k_ < 4; ++k_) { \
        bf16x8 x0_ = *(const bf16x8*)(y0_ + k_ * 32); \
        bf16x8 x1_ = *(const bf16x8*)(y1_ + k_ * 32); \
        _Pragma("unroll") for (int j_ = 0; j_ < 8; ++j_) \
          accf[k_][j_] += d0_ * bf2f((unsigned short)x0_[j_]) + d1_ * bf2f((unsigned short)x1_[j_]); \
      } \
    } \
  } \
  _Pragma("unroll") for (int j_ = 0; j_ < 8; ++j_) { \
    accf[0][j_] += P##c0 * bf2f((unsigned short)P##g0[j_])  + P##c1 * bf2f((unsigned short)P##g4[j_]) \
                 + P##c2 * bf2f((unsigned short)P##g8[j_])  + P##c3 * bf2f((unsigned short)P##g12[j_]); \
    accf[1][j_] += P##c0 * bf2f((unsigned short)P##g1[j_])  + P##c1 * bf2f((unsigned short)P##g5[j_]) \
                 + P##c2 * bf2f((unsigned short)P##g9[j_])  + P##c3 * bf2f((unsigned short)P##g13[j_]); \
    accf[2][j_] += P##c0 * bf2f((unsigned short)P##g2[j_])  + P##c1 * bf2f((unsigned short)P##g6[j_]) \
                 + P##c2 * bf2f((unsigned short)P##g10[j_]) + P##c3 * bf2f((unsigned short)P##g14[j_]); \
    accf[3][j_] += P##c0 * bf2f((unsigned short)P##g3[j_])  + P##c1 * bf2f((unsigned short)P##g7[j_]) \
                 + P##c2 * bf2f((unsigned short)P##g11[j_]) + P##c3 * bf2f((unsigned short)P##g15[j_]); \
  } \
  _Pragma("unroll") for (int k_ = 0; k_ < 4; ++k_) { \
    union { bf16x8 v; unsigned short s[8]; } u_; \
    _Pragma("unroll") for (int j_ = 0; j_ < 8; ++j_) u_.s[j_] = f2bf(accf[k_][j_]); \
    *(bf16x8*)((DSTP) + (k_ << 6) * 8) = u_.v; \
  } \
} while (0)

// producer end-of-tile sync: drain LDS writes only; global loads stay in
// flight across the barrier (no vmcnt drain -- the point of the pipeline).
#define P_BARRIER() do { \
  asm volatile("s_waitcnt lgkmcnt(0)"); \
  __builtin_amdgcn_sched_barrier(0); \
  __builtin_amdgcn_s_barrier(); \
} while (0)

// ======== persistent producer/consumer fused kernel =========================
// 256 blocks x 8 waves. Waves 0-3 (producers, one relation each): 2-tile-deep
// software pipeline -- tile it+1's 16 gathers issued before tile it's VALU
// accumulation; rec quad prefetched 2 tiles ahead. All pipeline state in
// NAMED registers (no arrays -> no scratch). Waves 4-7 (consumers): MFMA +
// epilogue of tile it-1 from the other LDS buffer. One barrier per tile.
__global__ __launch_bounds__(TPB, 2) void fused_kernel(
    const unsigned short* __restrict__ hb,     // [N][128] bf16
    const int2* __restrict__ rec2,             // [R][TILES][16][4] {src, s_out}
    const int2* __restrict__ ovf,              // [NROWS][OVFS] overflow records
    const int* __restrict__ cnt,               // [NROWS] in-degree (may exceed CAP)
    const unsigned short* __restrict__ Wt,     // layer: [R][128 col][128 k] bf16
    const float* __restrict__ bmean,           // [128]
    const unsigned short* __restrict__ resid_bf,
    float* __restrict__ out_f,
    unsigned short* __restrict__ out_bf) {
  __shared__ unsigned short t_lds[2][R * 4 * 64 * 8];  // 2 x 16 KB
  const int w = threadIdx.x >> 6;
  const int lane = threadIdx.x & 63;
  const int m = lane & 15;
  const int q = lane >> 4;
  const int bid = blockIdx.x;
  const int nt = (TILES - bid + GRID - 1) / GRID;   // >= 24 tiles for every block

  if (w < 4) {
    // -------------------- producer: relation w --------------------
    const int r = w;
    DECL_ST(A);
    DECL_ST(B);
    int cnA = 0, cnB = 0;
    i32x4 ra0, ra1, rb0, rb1;

    // prologue: rec+gathers for tile0 (stage A); rec for tile1 in flight
    P_LOADREC(cnA, ra0, ra1, bid);
    P_ISSUE(A, cnA, ra0, ra1, bid);
    if (nt > 1) P_LOADREC(cnB, rb0, rb1, bid + GRID);

    int it = 0;
    for (;;) {
      {  // even iteration: consume stage A, refill stage B
        const int tcur = bid + it * GRID;
        if (it + 1 < nt) {
          P_ISSUE(B, cnB, rb0, rb1, tcur + GRID);
          if (it + 2 < nt) P_LOADREC(cnA, ra0, ra1, tcur + 2 * GRID);
        }
        unsigned short* dstp = &t_lds[it & 1][(((r * 4) << 6) + lane) * 8];
        P_ACCUM(A, tcur, dstp);
        P_BARRIER();
        if (++it >= nt) break;
      }
      {  // odd iteration: consume stage B, refill stage A
        const int tcur = bid + it * GRID;
        if (it + 1 < nt) {
          P_ISSUE(A, cnA, ra0, ra1, tcur + GRID);
          if (it + 2 < nt) P_LOADREC(cnB, rb0, rb1, tcur + 2 * GRID);
        }
        unsigned short* dstp = &t_lds[it & 1][(((r * 4) << 6) + lane) * 8];
        P_ACCUM(B, tcur, dstp);
        P_BARRIER();
        if (++it >= nt) break;
      }
    }
    asm volatile("s_waitcnt lgkmcnt(0)");
    __builtin_amdgcn_s_barrier();                 // match consumer's nt+1 barriers
  } else {
    // -------------------- consumer: cols [cw*32, cw*32+32) --------------------
    const int cw = w - 4;
    bf16x8 breg[R][4][2];
#pragma unroll
    for (int r = 0; r < R; ++r) {
      const unsigned short* wr = Wt + ((size_t)r << 14);
#pragma unroll
      for (int ks = 0; ks < 4; ++ks)
#pragma unroll
        for (int c = 0; c < 2; ++c) {
          int ct = cw * 2 + c;
          breg[r][ks][c] = *(const bf16x8*)(wr + ((ct * 16 + m) << 7) + ks * 32 + q * 8);
        }
    }
    for (int it = 0; it < nt + 1; ++it) {
      if (it > 0) {
        const int tile = bid + (it - 1) * GRID;
        const int pb = (it - 1) & 1;
        float oacc[2][4];
#pragma unroll
        for (int c = 0; c < 2; ++c)
#pragma unroll
          for (int i = 0; i < 4; ++i) oacc[c][i] = 0.f;
#pragma unroll
        for (int r = 0; r < R; ++r) {
          f32x4 acc2[2];
#pragma unroll
          for (int c = 0; c < 2; ++c) acc2[c] = (f32x4){0.f, 0.f, 0.f, 0.f};
#pragma unroll
          for (int ks = 0; ks < 4; ++ks) {
            bf16x8 a = *(const bf16x8*)&t_lds[pb][(((r * 4 + ks) << 6) + lane) * 8];
#pragma unroll
            for (int c = 0; c < 2; ++c)
              acc2[c] = __builtin_amdgcn_mfma_f32_16x16x32_bf16(a, breg[r][ks][c], acc2[c], 0, 0, 0);
          }
          // s_in computed inline from in-degree (no s_in array/pass)
          i32x4 ci = *(const i32x4*)(cnt + (size_t)r * N_NODES + tile * 16 + q * 4);
#pragma unroll
          for (int c = 0; c < 2; ++c)
#pragma unroll
            for (int i = 0; i < 4; ++i)
              oacc[c][i] += rsqrtf(fmaxf((float)ci[i], 1.0f)) * acc2[c][i];
        }
#pragma unroll
        for (int c = 0; c < 2; ++c) {
          int colx = (cw * 2 + c) * 16 + m;
          float bm = bmean[colx];
#pragma unroll
          for (int i = 0; i < 4; ++i) {
            int row = tile * 16 + q * 4 + i;
            float v = oacc[c][i] * 0.25f + bm;
            v = (v >= 0.f) ? v : 0.2f * v;
            if (resid_bf) v += bf2f(resid_bf[(size_t)row * D + colx]);
            if (out_f) out_f[(size_t)row * D + colx] = v;
            else       out_bf[(size_t)row * D + colx] = f2bf(v);
          }
        }
      }
      asm volatile("s_waitcnt lgkmcnt(0)");
      __builtin_amdgcn_s_barrier();
    }
  }
}

extern "C" void kernel_launch(void* const* d_in, const int* in_sizes, int n_in,
                              void* d_out, int out_size, void* d_ws, size_t ws_size,
                              hipStream_t stream) {
  const float* emb    = (const float*)d_in[0];
  const float* W      = (const float*)d_in[1];
  const float* biases = (const float*)d_in[2];
  const int*   edges  = (const int*)d_in[3];
  float* out = (float*)d_out;
  char* ws = (char*)d_ws;

  size_t off = 0;
  auto alloc = [&](size_t bytes) { size_t o = off; off += (bytes + 255) & ~255ull; return o; };
  // only the int arrays (deg_i | cursor) need zeroing -> 3.2 MB memset
  int* ints      = (int*)(ws + alloc((size_t)2 * NROWS * 4));   // [deg_i | cursor]
  int* deg_i     = ints;
  int* cursor    = ints + NROWS;
  size_t zero_bytes = off;
  int2* rec2     = (int2*)(ws + alloc((size_t)R * TILES * 16 * 4 * 8));  // 12.8 MB, NOT zeroed
  int2* ovf      = (int2*)(ws + alloc((size_t)NROWS * OVFS * 8));        // 38.4 MB, NOT zeroed
  unsigned short* hb  = (unsigned short*)(ws + alloc((size_t)N_NODES * D * 2));
  unsigned short* hb2 = (unsigned short*)(ws + alloc((size_t)N_NODES * D * 2));
  unsigned short* Wt  = (unsigned short*)(ws + alloc((size_t)LAYERS * R * D * D * 2));
  float* bmean   = (float*)(ws + alloc((size_t)LAYERS * D * 4));
  (void)ws_size;

  // ---- prep: memset -> prep1(count+conversions) -> fill (3 dispatches) ----
  hipMemsetAsync(ws, 0, zero_bytes, stream);
  prep1_kernel<<<(N_NODES * D / 4 + 255) / 256, 256, 0, stream>>>(
      emb, W, biases, edges, deg_i, hb, Wt, bmean);
  fill_kernel<<<dim3((NE + 255) / 256, R), 256, 0, stream>>>(edges, deg_i, cursor, rec2, ovf);

  // layer 0: emb(bf16) -> hb2(bf16), no residual
  fused_kernel<<<GRID, TPB, 0, stream>>>(
      hb, rec2, ovf, cursor, Wt, bmean, nullptr, nullptr, hb2);
  // layer 1: hb2 -> out(fp32), residual = hb2
  fused_kernel<<<GRID, TPB, 0, stream>>>(
      hb2, rec2, ovf, cursor, Wt + (size_t)R * D * D, bmean + D, hb2, out, nullptr);
}